// Round 1
// baseline (949.883 us; speedup 1.0000x reference)
//
#include <hip/hip_runtime.h>

#define HDIM 128

// ---------- degree histogram ----------
__global__ void deg_kernel(const int* __restrict__ src, const int* __restrict__ dst,
                           int* __restrict__ deg_out, int* __restrict__ deg_in, int E) {
    int e = blockIdx.x * blockDim.x + threadIdx.x;
    if (e < E) {
        atomicAdd(&deg_out[src[e]], 1);
        atomicAdd(&deg_in[dst[e]], 1);
    }
}

// ---------- inverse-sqrt degree ----------
__global__ void inv_kernel(const int* __restrict__ deg_out, const int* __restrict__ deg_in,
                           float* __restrict__ inv_out, float* __restrict__ inv_in, int N) {
    int n = blockIdx.x * blockDim.x + threadIdx.x;
    if (n < N) {
        float dO = (float)(deg_out[n] > 1 ? deg_out[n] : 1);
        float dI = (float)(deg_in[n]  > 1 ? deg_in[n]  : 1);
        inv_out[n] = 1.0f / sqrtf(dO);
        inv_in[n]  = 1.0f / sqrtf(dI);
    }
}

// ---------- single-block looping prefix scan: row_ptr[i+1] = sum(deg_in[0..i]) ----------
__global__ void scan_kernel(const int* __restrict__ deg_in, int* __restrict__ row_ptr, int n) {
    __shared__ int buf[1024];
    __shared__ int carry_s;
    int tid = threadIdx.x;
    if (tid == 0) { row_ptr[0] = 0; carry_s = 0; }
    __syncthreads();
    for (int base = 0; base < n; base += 1024) {
        int i = base + tid;
        int v = (i < n) ? deg_in[i] : 0;
        buf[tid] = v;
        __syncthreads();
        // Hillis-Steele inclusive scan
        for (int offset = 1; offset < 1024; offset <<= 1) {
            int t = (tid >= offset) ? buf[tid - offset] : 0;
            __syncthreads();
            buf[tid] += t;
            __syncthreads();
        }
        int carry = carry_s;
        if (i < n) row_ptr[i + 1] = carry + buf[tid];
        __syncthreads();
        if (tid == 1023) carry_s = carry + buf[1023];
        __syncthreads();
    }
}

// ---------- init fill positions ----------
__global__ void pos_kernel(const int* __restrict__ row_ptr, int* __restrict__ pos, int N) {
    int n = blockIdx.x * blockDim.x + threadIdx.x;
    if (n < N) pos[n] = row_ptr[n];
}

// ---------- scatter edges into CSR (grouped by dst) ----------
__global__ void fill_kernel(const int* __restrict__ src, const int* __restrict__ dst,
                            int* __restrict__ pos, int* __restrict__ csr_src, int E) {
    int e = blockIdx.x * blockDim.x + threadIdx.x;
    if (e < E) {
        int d = dst[e];
        int idx = atomicAdd(&pos[d], 1);
        csr_src[idx] = src[e];
    }
}

// ---------- embedding gather: x[n] = z_table[z[n]] ----------
__global__ void embed_kernel(const int* __restrict__ z, const float* __restrict__ z_table,
                             float* __restrict__ x, int N) {
    int t = blockIdx.x * blockDim.x + threadIdx.x;
    int n = t >> 5;          // 32 float4 per row (H=128)
    int c = t & 31;
    if (n < N) {
        int zz = z[n];
        reinterpret_cast<float4*>(x)[(size_t)n * 32 + c] =
            reinterpret_cast<const float4*>(z_table)[(size_t)zz * 32 + c];
    }
}

// ---------- pull-based GraphConv: one wave (64 lanes) per dst node, float2 per lane ----------
__global__ __launch_bounds__(256) void conv_kernel(
        const float* __restrict__ x, float* __restrict__ out,
        const int* __restrict__ row_ptr, const int* __restrict__ csr_src,
        const float* __restrict__ inv_out, const float* __restrict__ inv_in,
        const float* __restrict__ bias, int N, int do_relu) {
    int gtid = blockIdx.x * blockDim.x + threadIdx.x;
    int n = gtid >> 6;       // wave per node
    int lane = threadIdx.x & 63;
    if (n >= N) return;

    int start = row_ptr[n];
    int end   = row_ptr[n + 1];
    float2 acc = make_float2(0.0f, 0.0f);
    for (int e = start; e < end; ++e) {
        int s = csr_src[e];
        float w = inv_out[s];
        float2 v = reinterpret_cast<const float2*>(x + (size_t)s * HDIM)[lane];
        acc.x += w * v.x;
        acc.y += w * v.y;
    }
    float win = inv_in[n];
    float2 b = reinterpret_cast<const float2*>(bias)[lane];
    float2 o;
    o.x = acc.x * win + b.x;
    o.y = acc.y * win + b.y;
    if (do_relu) { o.x = fmaxf(o.x, 0.0f); o.y = fmaxf(o.y, 0.0f); }
    reinterpret_cast<float2*>(out + (size_t)n * HDIM)[lane] = o;
}

// ---------- center pooling + 2-layer MLP: one block (128 thr) per pair ----------
__global__ __launch_bounds__(128) void mlp_kernel(
        const float* __restrict__ x, const int* __restrict__ pairs,
        const float* __restrict__ W1, const float* __restrict__ b1,
        const float* __restrict__ W2, const float* __restrict__ b2,
        float* __restrict__ out, int B) {
    __shared__ float xp[HDIM];
    __shared__ float red[HDIM];
    int p = blockIdx.x;
    int t = threadIdx.x;
    int a = pairs[p];
    int bnode = pairs[B + p];
    xp[t] = x[(size_t)a * HDIM + t] * x[(size_t)bnode * HDIM + t];
    __syncthreads();
    float h = b1[t];
    #pragma unroll 8
    for (int k = 0; k < HDIM; ++k) h += xp[k] * W1[k * HDIM + t];
    h = fmaxf(h, 0.0f);
    red[t] = h * W2[t];
    __syncthreads();
    for (int s = 64; s > 0; s >>= 1) {
        if (t < s) red[t] += red[t + s];
        __syncthreads();
    }
    if (t == 0) out[p] = red[0] + b2[0];
}

extern "C" void kernel_launch(void* const* d_in, const int* in_sizes, int n_in,
                              void* d_out, int out_size, void* d_ws, size_t ws_size,
                              hipStream_t stream) {
    const int*   z       = (const int*)d_in[0];
    const int*   src     = (const int*)d_in[1];
    const int*   dst     = (const int*)d_in[2];
    const int*   pairs   = (const int*)d_in[3];
    const float* z_table = (const float*)d_in[4];
    const float* bias[3] = {(const float*)d_in[5], (const float*)d_in[6], (const float*)d_in[7]};
    const float* W1      = (const float*)d_in[8];
    const float* b1      = (const float*)d_in[9];
    const float* W2      = (const float*)d_in[10];
    const float* b2      = (const float*)d_in[11];

    const int N = in_sizes[0];
    const int E = in_sizes[1];
    const int B = in_sizes[3] / 2;

    // workspace carve-out
    char* ws = (char*)d_ws;
    size_t off = 0;
    auto carve = [&](size_t bytes) -> void* {
        void* p = ws + off;
        off = (off + bytes + 255) & ~(size_t)255;
        return p;
    };
    int*   deg_out = (int*)carve((size_t)N * 4);
    int*   deg_in  = (int*)carve((size_t)N * 4);
    float* inv_out = (float*)carve((size_t)N * 4);
    float* inv_in  = (float*)carve((size_t)N * 4);
    int*   row_ptr = (int*)carve((size_t)(N + 1) * 4);
    int*   pos     = (int*)carve((size_t)N * 4);
    int*   csr_src = (int*)carve((size_t)E * 4);
    float* xb      = (float*)carve((size_t)N * HDIM * 4);
    float* mb      = (float*)carve((size_t)N * HDIM * 4);

    hipMemsetAsync(deg_out, 0, (size_t)N * 4, stream);
    hipMemsetAsync(deg_in,  0, (size_t)N * 4, stream);

    deg_kernel<<<(E + 255) / 256, 256, 0, stream>>>(src, dst, deg_out, deg_in, E);
    inv_kernel<<<(N + 255) / 256, 256, 0, stream>>>(deg_out, deg_in, inv_out, inv_in, N);
    scan_kernel<<<1, 1024, 0, stream>>>(deg_in, row_ptr, N);
    pos_kernel<<<(N + 255) / 256, 256, 0, stream>>>(row_ptr, pos, N);
    fill_kernel<<<(E + 255) / 256, 256, 0, stream>>>(src, dst, pos, csr_src, E);
    embed_kernel<<<((size_t)N * 32 + 255) / 256, 256, 0, stream>>>(z, z_table, xb, N);

    float* cur = xb;
    float* nxt = mb;
    for (int layer = 0; layer < 3; ++layer) {
        int do_relu = (layer < 2) ? 1 : 0;
        long long threads = (long long)N * 64;
        conv_kernel<<<(threads + 255) / 256, 256, 0, stream>>>(
            cur, nxt, row_ptr, csr_src, inv_out, inv_in, bias[layer], N, do_relu);
        float* tmp = cur; cur = nxt; nxt = tmp;
    }

    mlp_kernel<<<B, 128, 0, stream>>>(cur, pairs, W1, b1, W2, b2, (float*)d_out, B);
}

// Round 2
// 789.766 us; speedup vs baseline: 1.2027x; 1.2027x over previous
//
#include <hip/hip_runtime.h>

#define HDIM 128
#define SCAN_CHUNK 1024

// ---------- degree histogram ----------
__global__ void deg_kernel(const int* __restrict__ src, const int* __restrict__ dst,
                           int* __restrict__ deg_out, int* __restrict__ deg_in, int E) {
    int e = blockIdx.x * blockDim.x + threadIdx.x;
    if (e < E) {
        atomicAdd(&deg_out[src[e]], 1);
        atomicAdd(&deg_in[dst[e]], 1);
    }
}

// ---------- inverse-sqrt degree ----------
__global__ void inv_kernel(const int* __restrict__ deg_out, const int* __restrict__ deg_in,
                           float* __restrict__ inv_out, float* __restrict__ inv_in, int N) {
    int n = blockIdx.x * blockDim.x + threadIdx.x;
    if (n < N) {
        float dO = (float)(deg_out[n] > 1 ? deg_out[n] : 1);
        float dI = (float)(deg_in[n]  > 1 ? deg_in[n]  : 1);
        inv_out[n] = 1.0f / sqrtf(dO);
        inv_in[n]  = 1.0f / sqrtf(dI);
    }
}

// ---------- hierarchical scan pass 1: per-block sums ----------
__global__ __launch_bounds__(1024) void scan_blk_sum(const int* __restrict__ deg,
                                                     int* __restrict__ blk_sum, int n) {
    __shared__ int red[1024];
    int tid = threadIdx.x;
    int i = blockIdx.x * SCAN_CHUNK + tid;
    red[tid] = (i < n) ? deg[i] : 0;
    __syncthreads();
    for (int s = 512; s > 0; s >>= 1) {
        if (tid < s) red[tid] += red[tid + s];
        __syncthreads();
    }
    if (tid == 0) blk_sum[blockIdx.x] = red[0];
}

// ---------- hierarchical scan pass 2: exclusive scan of block sums (nblk <= 128) ----------
__global__ __launch_bounds__(128) void scan_blk_off(const int* __restrict__ blk_sum,
                                                    int* __restrict__ blk_off, int nblk) {
    __shared__ int buf[128];
    int tid = threadIdx.x;
    int v = (tid < nblk) ? blk_sum[tid] : 0;
    buf[tid] = v;
    __syncthreads();
    for (int offset = 1; offset < 128; offset <<= 1) {
        int t = (tid >= offset) ? buf[tid - offset] : 0;
        __syncthreads();
        buf[tid] += t;
        __syncthreads();
    }
    if (tid < nblk) blk_off[tid] = buf[tid] - v;   // exclusive
}

// ---------- hierarchical scan pass 3: per-block inclusive scan + offset ----------
// writes row_ptr[i+1] (inclusive) and pos[i] (exclusive); row_ptr[0]=0.
__global__ __launch_bounds__(1024) void scan_apply(const int* __restrict__ deg,
                                                   const int* __restrict__ blk_off,
                                                   int* __restrict__ row_ptr,
                                                   int* __restrict__ pos, int n) {
    __shared__ int buf[1024];
    int tid = threadIdx.x;
    int i = blockIdx.x * SCAN_CHUNK + tid;
    int v = (i < n) ? deg[i] : 0;
    buf[tid] = v;
    __syncthreads();
    for (int offset = 1; offset < 1024; offset <<= 1) {
        int t = (tid >= offset) ? buf[tid - offset] : 0;
        __syncthreads();
        buf[tid] += t;
        __syncthreads();
    }
    int base = blk_off[blockIdx.x];
    if (i < n) {
        int incl = base + buf[tid];
        row_ptr[i + 1] = incl;
        pos[i] = incl - v;
    }
    if (i == 0) row_ptr[0] = 0;
}

// ---------- scatter edges into CSR (grouped by dst) ----------
__global__ void fill_kernel(const int* __restrict__ src, const int* __restrict__ dst,
                            int* __restrict__ pos, int* __restrict__ csr_src, int E) {
    int e = blockIdx.x * blockDim.x + threadIdx.x;
    if (e < E) {
        int d = dst[e];
        int idx = atomicAdd(&pos[d], 1);
        csr_src[idx] = src[e];
    }
}

// ---------- embedding gather: x[n] = z_table[z[n]] ----------
__global__ void embed_kernel(const int* __restrict__ z, const float* __restrict__ z_table,
                             float* __restrict__ x, int N) {
    int t = blockIdx.x * blockDim.x + threadIdx.x;
    int n = t >> 5;          // 32 float4 per row (H=128)
    int c = t & 31;
    if (n < N) {
        int zz = z[n];
        reinterpret_cast<float4*>(x)[(size_t)n * 32 + c] =
            reinterpret_cast<const float4*>(z_table)[(size_t)zz * 32 + c];
    }
}

// ---------- pull-based GraphConv: one wave (64 lanes) per dst node, float2 per lane ----------
__global__ __launch_bounds__(256) void conv_kernel(
        const float* __restrict__ x, float* __restrict__ out,
        const int* __restrict__ row_ptr, const int* __restrict__ csr_src,
        const float* __restrict__ inv_out, const float* __restrict__ inv_in,
        const float* __restrict__ bias, int N, int do_relu) {
    int gtid = blockIdx.x * blockDim.x + threadIdx.x;
    int n = gtid >> 6;       // wave per node
    int lane = threadIdx.x & 63;
    if (n >= N) return;

    int start = row_ptr[n];
    int end   = row_ptr[n + 1];
    float2 acc = make_float2(0.0f, 0.0f);
    for (int e = start; e < end; ++e) {
        int s = csr_src[e];
        float w = inv_out[s];
        float2 v = reinterpret_cast<const float2*>(x + (size_t)s * HDIM)[lane];
        acc.x += w * v.x;
        acc.y += w * v.y;
    }
    float win = inv_in[n];
    float2 b = reinterpret_cast<const float2*>(bias)[lane];
    float2 o;
    o.x = acc.x * win + b.x;
    o.y = acc.y * win + b.y;
    if (do_relu) { o.x = fmaxf(o.x, 0.0f); o.y = fmaxf(o.y, 0.0f); }
    reinterpret_cast<float2*>(out + (size_t)n * HDIM)[lane] = o;
}

// ---------- center pooling + 2-layer MLP: one block (128 thr) per pair ----------
__global__ __launch_bounds__(128) void mlp_kernel(
        const float* __restrict__ x, const int* __restrict__ pairs,
        const float* __restrict__ W1, const float* __restrict__ b1,
        const float* __restrict__ W2, const float* __restrict__ b2,
        float* __restrict__ out, int B) {
    __shared__ float xp[HDIM];
    __shared__ float red[HDIM];
    int p = blockIdx.x;
    int t = threadIdx.x;
    int a = pairs[p];
    int bnode = pairs[B + p];
    xp[t] = x[(size_t)a * HDIM + t] * x[(size_t)bnode * HDIM + t];
    __syncthreads();
    float h = b1[t];
    #pragma unroll 8
    for (int k = 0; k < HDIM; ++k) h += xp[k] * W1[k * HDIM + t];
    h = fmaxf(h, 0.0f);
    red[t] = h * W2[t];
    __syncthreads();
    for (int s = 64; s > 0; s >>= 1) {
        if (t < s) red[t] += red[t + s];
        __syncthreads();
    }
    if (t == 0) out[p] = red[0] + b2[0];
}

extern "C" void kernel_launch(void* const* d_in, const int* in_sizes, int n_in,
                              void* d_out, int out_size, void* d_ws, size_t ws_size,
                              hipStream_t stream) {
    const int*   z       = (const int*)d_in[0];
    const int*   src     = (const int*)d_in[1];
    const int*   dst     = (const int*)d_in[2];
    const int*   pairs   = (const int*)d_in[3];
    const float* z_table = (const float*)d_in[4];
    const float* bias[3] = {(const float*)d_in[5], (const float*)d_in[6], (const float*)d_in[7]};
    const float* W1      = (const float*)d_in[8];
    const float* b1      = (const float*)d_in[9];
    const float* W2      = (const float*)d_in[10];
    const float* b2      = (const float*)d_in[11];

    const int N = in_sizes[0];
    const int E = in_sizes[1];
    const int B = in_sizes[3] / 2;
    const int nblk = (N + SCAN_CHUNK - 1) / SCAN_CHUNK;   // 98 for N=100000 (must be <=128)

    // workspace carve-out
    char* ws = (char*)d_ws;
    size_t off = 0;
    auto carve = [&](size_t bytes) -> void* {
        void* p = ws + off;
        off = (off + bytes + 255) & ~(size_t)255;
        return p;
    };
    int*   deg_out = (int*)carve((size_t)N * 4);
    int*   deg_in  = (int*)carve((size_t)N * 4);
    float* inv_out = (float*)carve((size_t)N * 4);
    float* inv_in  = (float*)carve((size_t)N * 4);
    int*   row_ptr = (int*)carve((size_t)(N + 1) * 4);
    int*   pos     = (int*)carve((size_t)N * 4);
    int*   blk_sum = (int*)carve((size_t)nblk * 4);
    int*   blk_off = (int*)carve((size_t)nblk * 4);
    int*   csr_src = (int*)carve((size_t)E * 4);
    float* xb      = (float*)carve((size_t)N * HDIM * 4);
    float* mb      = (float*)carve((size_t)N * HDIM * 4);

    hipMemsetAsync(deg_out, 0, (size_t)N * 4, stream);
    hipMemsetAsync(deg_in,  0, (size_t)N * 4, stream);

    deg_kernel<<<(E + 255) / 256, 256, 0, stream>>>(src, dst, deg_out, deg_in, E);
    inv_kernel<<<(N + 255) / 256, 256, 0, stream>>>(deg_out, deg_in, inv_out, inv_in, N);

    scan_blk_sum<<<nblk, 1024, 0, stream>>>(deg_in, blk_sum, N);
    scan_blk_off<<<1, 128, 0, stream>>>(blk_sum, blk_off, nblk);
    scan_apply<<<nblk, 1024, 0, stream>>>(deg_in, blk_off, row_ptr, pos, N);

    fill_kernel<<<(E + 255) / 256, 256, 0, stream>>>(src, dst, pos, csr_src, E);
    embed_kernel<<<((size_t)N * 32 + 255) / 256, 256, 0, stream>>>(z, z_table, xb, N);

    float* cur = xb;
    float* nxt = mb;
    for (int layer = 0; layer < 3; ++layer) {
        int do_relu = (layer < 2) ? 1 : 0;
        long long threads = (long long)N * 64;
        conv_kernel<<<(threads + 255) / 256, 256, 0, stream>>>(
            cur, nxt, row_ptr, csr_src, inv_out, inv_in, bias[layer], N, do_relu);
        float* tmp = cur; cur = nxt; nxt = tmp;
    }

    mlp_kernel<<<B, 128, 0, stream>>>(cur, pairs, W1, b1, W2, b2, (float*)d_out, B);
}

// Round 3
// 625.616 us; speedup vs baseline: 1.5183x; 1.2624x over previous
//
#include <hip/hip_runtime.h>

#define HDIM 128
#define SCAN_CHUNK 1024

// ---------- degree histogram ----------
__global__ void deg_kernel(const int* __restrict__ src, const int* __restrict__ dst,
                           int* __restrict__ deg_out, int* __restrict__ deg_in, int E) {
    int e = blockIdx.x * blockDim.x + threadIdx.x;
    if (e < E) {
        atomicAdd(&deg_out[src[e]], 1);
        atomicAdd(&deg_in[dst[e]], 1);
    }
}

// ---------- inverse-sqrt degree ----------
__global__ void inv_kernel(const int* __restrict__ deg_out, const int* __restrict__ deg_in,
                           float* __restrict__ inv_out, float* __restrict__ inv_in, int N) {
    int n = blockIdx.x * blockDim.x + threadIdx.x;
    if (n < N) {
        float dO = (float)(deg_out[n] > 1 ? deg_out[n] : 1);
        float dI = (float)(deg_in[n]  > 1 ? deg_in[n]  : 1);
        inv_out[n] = 1.0f / sqrtf(dO);
        inv_in[n]  = 1.0f / sqrtf(dI);
    }
}

// ---------- hierarchical scan pass 1: per-block sums ----------
__global__ __launch_bounds__(1024) void scan_blk_sum(const int* __restrict__ deg,
                                                     int* __restrict__ blk_sum, int n) {
    __shared__ int red[1024];
    int tid = threadIdx.x;
    int i = blockIdx.x * SCAN_CHUNK + tid;
    red[tid] = (i < n) ? deg[i] : 0;
    __syncthreads();
    for (int s = 512; s > 0; s >>= 1) {
        if (tid < s) red[tid] += red[tid + s];
        __syncthreads();
    }
    if (tid == 0) blk_sum[blockIdx.x] = red[0];
}

// ---------- hierarchical scan pass 2: exclusive scan of block sums (nblk <= 128) ----------
__global__ __launch_bounds__(128) void scan_blk_off(const int* __restrict__ blk_sum,
                                                    int* __restrict__ blk_off, int nblk) {
    __shared__ int buf[128];
    int tid = threadIdx.x;
    int v = (tid < nblk) ? blk_sum[tid] : 0;
    buf[tid] = v;
    __syncthreads();
    for (int offset = 1; offset < 128; offset <<= 1) {
        int t = (tid >= offset) ? buf[tid - offset] : 0;
        __syncthreads();
        buf[tid] += t;
        __syncthreads();
    }
    if (tid < nblk) blk_off[tid] = buf[tid] - v;   // exclusive
}

// ---------- hierarchical scan pass 3: per-block inclusive scan + offset ----------
__global__ __launch_bounds__(1024) void scan_apply(const int* __restrict__ deg,
                                                   const int* __restrict__ blk_off,
                                                   int* __restrict__ row_ptr,
                                                   int* __restrict__ pos, int n) {
    __shared__ int buf[1024];
    int tid = threadIdx.x;
    int i = blockIdx.x * SCAN_CHUNK + tid;
    int v = (i < n) ? deg[i] : 0;
    buf[tid] = v;
    __syncthreads();
    for (int offset = 1; offset < 1024; offset <<= 1) {
        int t = (tid >= offset) ? buf[tid - offset] : 0;
        __syncthreads();
        buf[tid] += t;
        __syncthreads();
    }
    int base = blk_off[blockIdx.x];
    if (i < n) {
        int incl = base + buf[tid];
        row_ptr[i + 1] = incl;
        pos[i] = incl - v;
    }
    if (i == 0) row_ptr[0] = 0;
}

// ---------- scatter edges into CSR (grouped by dst) ----------
__global__ void fill_kernel(const int* __restrict__ src, const int* __restrict__ dst,
                            int* __restrict__ pos, int* __restrict__ csr_src, int E) {
    int e = blockIdx.x * blockDim.x + threadIdx.x;
    if (e < E) {
        int d = dst[e];
        int idx = atomicAdd(&pos[d], 1);
        csr_src[idx] = src[e];
    }
}

// ---------- embedding gather, pre-scaled: x[n] = z_table[z[n]] * inv_out[n] ----------
__global__ void embed_kernel(const int* __restrict__ z, const float* __restrict__ z_table,
                             const float* __restrict__ inv_out,
                             float* __restrict__ x, int N) {
    int t = blockIdx.x * blockDim.x + threadIdx.x;
    int n = t >> 5;          // 32 float4 per row (H=128)
    int c = t & 31;
    if (n < N) {
        int zz = z[n];
        float w = inv_out[n];
        float4 v = reinterpret_cast<const float4*>(z_table)[(size_t)zz * 32 + c];
        v.x *= w; v.y *= w; v.z *= w; v.w *= w;
        reinterpret_cast<float4*>(x)[(size_t)n * 32 + c] = v;
    }
}

// ---------- pull-based GraphConv, 4-way unrolled ----------
// input xs is PRE-SCALED by inv_out. mode 0: out = relu(acc*inv_in+b)*inv_out (feeds next conv)
//                                    mode 1: out = acc*inv_in+b              (final layer)
__global__ __launch_bounds__(256) void conv_kernel(
        const float* __restrict__ xs, float* __restrict__ out,
        const int* __restrict__ row_ptr, const int* __restrict__ csr_src,
        const float* __restrict__ inv_out, const float* __restrict__ inv_in,
        const float* __restrict__ bias, int N, int mode) {
    int gtid = blockIdx.x * blockDim.x + threadIdx.x;
    int n = gtid >> 6;       // wave per node
    int lane = threadIdx.x & 63;
    if (n >= N) return;

    int start = row_ptr[n];
    int end   = row_ptr[n + 1];

    float2 acc0 = make_float2(0.f, 0.f), acc1 = acc0, acc2 = acc0, acc3 = acc0;
    int e = start;
    for (; e + 4 <= end; e += 4) {
        int s0 = csr_src[e + 0];
        int s1 = csr_src[e + 1];
        int s2 = csr_src[e + 2];
        int s3 = csr_src[e + 3];
        float2 v0 = reinterpret_cast<const float2*>(xs + (size_t)s0 * HDIM)[lane];
        float2 v1 = reinterpret_cast<const float2*>(xs + (size_t)s1 * HDIM)[lane];
        float2 v2 = reinterpret_cast<const float2*>(xs + (size_t)s2 * HDIM)[lane];
        float2 v3 = reinterpret_cast<const float2*>(xs + (size_t)s3 * HDIM)[lane];
        acc0.x += v0.x; acc0.y += v0.y;
        acc1.x += v1.x; acc1.y += v1.y;
        acc2.x += v2.x; acc2.y += v2.y;
        acc3.x += v3.x; acc3.y += v3.y;
    }
    for (; e < end; ++e) {
        int s = csr_src[e];
        float2 v = reinterpret_cast<const float2*>(xs + (size_t)s * HDIM)[lane];
        acc0.x += v.x; acc0.y += v.y;
    }
    float2 acc;
    acc.x = (acc0.x + acc1.x) + (acc2.x + acc3.x);
    acc.y = (acc0.y + acc1.y) + (acc2.y + acc3.y);

    float win = inv_in[n];
    float2 b = reinterpret_cast<const float2*>(bias)[lane];
    float2 o;
    o.x = acc.x * win + b.x;
    o.y = acc.y * win + b.y;
    if (mode == 0) {
        float wout = inv_out[n];
        o.x = fmaxf(o.x, 0.0f) * wout;
        o.y = fmaxf(o.y, 0.0f) * wout;
    }
    reinterpret_cast<float2*>(out + (size_t)n * HDIM)[lane] = o;
}

// ---------- center pooling + 2-layer MLP: one block (128 thr) per pair ----------
__global__ __launch_bounds__(128) void mlp_kernel(
        const float* __restrict__ x, const int* __restrict__ pairs,
        const float* __restrict__ W1, const float* __restrict__ b1,
        const float* __restrict__ W2, const float* __restrict__ b2,
        float* __restrict__ out, int B) {
    __shared__ float xp[HDIM];
    __shared__ float red[HDIM];
    int p = blockIdx.x;
    int t = threadIdx.x;
    int a = pairs[p];
    int bnode = pairs[B + p];
    xp[t] = x[(size_t)a * HDIM + t] * x[(size_t)bnode * HDIM + t];
    __syncthreads();
    float h = b1[t];
    #pragma unroll 8
    for (int k = 0; k < HDIM; ++k) h += xp[k] * W1[k * HDIM + t];
    h = fmaxf(h, 0.0f);
    red[t] = h * W2[t];
    __syncthreads();
    for (int s = 64; s > 0; s >>= 1) {
        if (t < s) red[t] += red[t + s];
        __syncthreads();
    }
    if (t == 0) out[p] = red[0] + b2[0];
}

extern "C" void kernel_launch(void* const* d_in, const int* in_sizes, int n_in,
                              void* d_out, int out_size, void* d_ws, size_t ws_size,
                              hipStream_t stream) {
    const int*   z       = (const int*)d_in[0];
    const int*   src     = (const int*)d_in[1];
    const int*   dst     = (const int*)d_in[2];
    const int*   pairs   = (const int*)d_in[3];
    const float* z_table = (const float*)d_in[4];
    const float* bias[3] = {(const float*)d_in[5], (const float*)d_in[6], (const float*)d_in[7]};
    const float* W1      = (const float*)d_in[8];
    const float* b1      = (const float*)d_in[9];
    const float* W2      = (const float*)d_in[10];
    const float* b2      = (const float*)d_in[11];

    const int N = in_sizes[0];
    const int E = in_sizes[1];
    const int B = in_sizes[3] / 2;
    const int nblk = (N + SCAN_CHUNK - 1) / SCAN_CHUNK;

    char* ws = (char*)d_ws;
    size_t off = 0;
    auto carve = [&](size_t bytes) -> void* {
        void* p = ws + off;
        off = (off + bytes + 255) & ~(size_t)255;
        return p;
    };
    int*   deg_out = (int*)carve((size_t)N * 4);
    int*   deg_in  = (int*)carve((size_t)N * 4);
    float* inv_out = (float*)carve((size_t)N * 4);
    float* inv_in  = (float*)carve((size_t)N * 4);
    int*   row_ptr = (int*)carve((size_t)(N + 1) * 4);
    int*   pos     = (int*)carve((size_t)N * 4);
    int*   blk_sum = (int*)carve((size_t)nblk * 4);
    int*   blk_off = (int*)carve((size_t)nblk * 4);
    int*   csr_src = (int*)carve((size_t)E * 4);
    float* xb      = (float*)carve((size_t)N * HDIM * 4);
    float* mb      = (float*)carve((size_t)N * HDIM * 4);

    hipMemsetAsync(deg_out, 0, (size_t)N * 4, stream);
    hipMemsetAsync(deg_in,  0, (size_t)N * 4, stream);

    deg_kernel<<<(E + 255) / 256, 256, 0, stream>>>(src, dst, deg_out, deg_in, E);
    inv_kernel<<<(N + 255) / 256, 256, 0, stream>>>(deg_out, deg_in, inv_out, inv_in, N);

    scan_blk_sum<<<nblk, 1024, 0, stream>>>(deg_in, blk_sum, N);
    scan_blk_off<<<1, 128, 0, stream>>>(blk_sum, blk_off, nblk);
    scan_apply<<<nblk, 1024, 0, stream>>>(deg_in, blk_off, row_ptr, pos, N);

    fill_kernel<<<(E + 255) / 256, 256, 0, stream>>>(src, dst, pos, csr_src, E);
    embed_kernel<<<((size_t)N * 32 + 255) / 256, 256, 0, stream>>>(z, z_table, inv_out, xb, N);

    float* cur = xb;
    float* nxt = mb;
    for (int layer = 0; layer < 3; ++layer) {
        int mode = (layer < 2) ? 0 : 1;
        long long threads = (long long)N * 64;
        conv_kernel<<<(threads + 255) / 256, 256, 0, stream>>>(
            cur, nxt, row_ptr, csr_src, inv_out, inv_in, bias[layer], N, mode);
        float* tmp = cur; cur = nxt; nxt = tmp;
    }

    mlp_kernel<<<B, 128, 0, stream>>>(cur, pairs, W1, b1, W2, b2, (float*)d_out, B);
}